// Round 10
// baseline (207.556 us; speedup 1.0000x reference)
//
#include <hip/hip_runtime.h>
#include <hip/hip_bf16.h>

#define N_ELEM 1000000
#define D 128
#define S_SEG 65536
#define SEGB 32                 // segments per block (one DRAM stream per block)
#define GRP 4                   // segments merged per barrier (== waves/block)
#define NBLK (S_SEG / SEGB)     // 2048 blocks = 2048 streams, 8192 waves total
#define NEG_BIG (-1e30f)

// 32-lane xor-reduce (offsets 1..16 never cross the 32-lane half).
__device__ __forceinline__ float halfReduce(float d) {
    #pragma unroll
    for (int off = 1; off <= 16; off <<= 1)
        d += __shfl_xor(d, off, 64);
    return d;
}

__device__ __forceinline__ float dot4(float4 v, float4 w) {
    return fmaf(v.x, w.x, fmaf(v.y, w.y, fmaf(v.z, w.z, v.w * w.w)));
}

// Online-softmax step; valid==false => exact no-op (p=0, m unchanged, scale=1).
__device__ __forceinline__ void osm_step(float& m, float& l, float4& a,
                                         float d, float4 v, bool valid) {
    float mn = valid ? fmaxf(m, d) : m;
    float scale = __expf(m - mn);
    float p = valid ? __expf(d - mn) : 0.f;
    m = mn;
    l = fmaf(l, scale, p);
    a.x = fmaf(a.x, scale, p * v.x);
    a.y = fmaf(a.y, scale, p * v.y);
    a.z = fmaf(a.z, scale, p * v.z);
    a.w = fmaf(a.w, scale, p * v.w);
}

// Merge state 2 into state 1 (associative; safe for empty states).
__device__ __forceinline__ void osm_merge(float& m1, float& l1, float4& a1,
                                          float m2, float l2, float4 a2) {
    float m = fmaxf(m1, m2);
    float s1 = __expf(m1 - m), s2 = __expf(m2 - m);
    l1 = l1 * s1 + l2 * s2;
    a1.x = a1.x * s1 + a2.x * s2;
    a1.y = a1.y * s1 + a2.y * s2;
    a1.z = a1.z * s1 + a2.z * s2;
    a1.w = a1.w * s1 + a2.w * s2;
    m1 = m;
}

// K1 (round-10): BLOCK-COOPERATIVE streams. Block b owns segments
// [b*32,(b+1)*32); its 4 waves interleave row-pairs within every segment
// (wave w takes pairs beg+8k+2w; lanes<32 row, lanes>=32 row+1; float4/lane).
// => 2048 dense streams, each a ~8KB-deep front of ADJACENT requests
// (DRAM row-buffer friendly), at FULL 8192-wave occupancy.
// Cross-wave combine: associative online-softmax merge via LDS, 4 segments
// per barrier. emb reads HBM exactly once; no atomics; no zero-init.
__global__ __launch_bounds__(256) void k_fused(
        const float* __restrict__ emb, const int* __restrict__ seg,
        const float* __restrict__ watt, float* __restrict__ out) {
    const int tid  = threadIdx.x;
    const int lane = tid & 63;
    const int w    = tid >> 6;          // wave 0..3
    const int half = lane >> 5;         // row parity within pair
    const int hl   = lane & 31;         // dims 4*hl..4*hl+3
    const float4 wv = reinterpret_cast<const float4*>(watt)[hl];
    const float4* emb4 = reinterpret_cast<const float4*>(emb);
    float4* out4 = reinterpret_cast<float4*>(out);

    __shared__ int    s_off[SEGB + 1];
    __shared__ float  s_m[GRP][GRP];
    __shared__ float  s_l[GRP][GRP];
    __shared__ float4 s_a[GRP][GRP][32];   // [src wave][seg-in-group][dim quad]

    const int s0 = blockIdx.x * SEGB;
    if (tid <= SEGB) {
        int target = s0 + tid, lo = 0, hi = N_ELEM;
        while (lo < hi) {
            int mid = (lo + hi) >> 1;
            if (seg[mid] < target) lo = mid + 1; else hi = mid;
        }
        s_off[tid] = lo;
    }
    __syncthreads();

    const float4 z4 = {0.f, 0.f, 0.f, 0.f};

    #pragma unroll 1
    for (int g = 0; g < SEGB / GRP; ++g) {
        float  m[GRP], l[GRP];
        float4 a[GRP], c[GRP];
        int    end[GRP], e[GRP];
        // prologue: 4 independent loads (one per segment), issued back-to-back
        #pragma unroll
        for (int j = 0; j < GRP; ++j) {
            int beg = s_off[g * GRP + j];
            end[j]  = s_off[g * GRP + j + 1];
            m[j] = NEG_BIG; l[j] = 0.f; a[j] = z4;
            e[j] = beg + 2 * w;
            c[j] = emb4[(size_t)min(e[j] + half, N_ELEM - 1) * 32 + hl];
        }
        #pragma unroll
        for (int j = 0; j < GRP; ++j) {
            #pragma unroll 1
            while (e[j] < end[j]) {
                int en = e[j] + 8;                      // this wave's next pair
                float4 cn = emb4[(size_t)min((en < end[j] ? en : e[j]) + half,
                                             N_ELEM - 1) * 32 + hl];
                float d = halfReduce(dot4(c[j], wv));
                osm_step(m[j], l[j], a[j], d, c[j], (e[j] + half) < end[j]);
                c[j] = cn; e[j] = en;
            }
        }
        // cross-half merge, publish per-wave states to LDS
        #pragma unroll
        for (int j = 0; j < GRP; ++j) {
            float  mo = __shfl_xor(m[j], 32, 64);
            float  lo = __shfl_xor(l[j], 32, 64);
            float4 ao;
            ao.x = __shfl_xor(a[j].x, 32, 64);
            ao.y = __shfl_xor(a[j].y, 32, 64);
            ao.z = __shfl_xor(a[j].z, 32, 64);
            ao.w = __shfl_xor(a[j].w, 32, 64);
            osm_merge(m[j], l[j], a[j], mo, lo, ao);
            if (lane == 0) { s_m[w][j] = m[j]; s_l[w][j] = l[j]; }
            if (half == 0) s_a[w][j][hl] = a[j];
        }
        __syncthreads();
        // wave w finalizes segment g*GRP+w: merge 4 wave-states, normalize, store
        {
            float  mm = s_m[0][w], ll = s_l[0][w];
            float4 aa = s_a[0][w][hl];
            #pragma unroll
            for (int t = 1; t < GRP; ++t)
                osm_merge(mm, ll, aa, s_m[t][w], s_l[t][w], s_a[t][w][hl]);
            float inv = (ll > 0.f) ? 1.0f / ll : 0.f;   // empty segment -> zeros
            if (half == 0) {
                float4 r = {aa.x * inv, aa.y * inv, aa.z * inv, aa.w * inv};
                out4[(size_t)(s0 + g * GRP + w) * 32 + hl] = r;
            }
        }
        __syncthreads();
    }
}

// K2: out[s,:] = h[s,:] @ w_out^T, in place per 128-row tile.
// LDS-staged, transposed with +4 padding to dodge bank conflicts.
#define PAD 132
__global__ __launch_bounds__(256) void k_proj(
        float* __restrict__ out, const float* __restrict__ wout) {
    __shared__ float As[128 * PAD];  // As[k*PAD + r] = h[r0+r][k]
    __shared__ float Bs[128 * PAD];  // Bs[k*PAD + j] = wout[j][k]
    const int tid = threadIdx.x;
    const int r0 = blockIdx.x * 128;
    for (int idx = tid; idx < 128 * 128; idx += 256) {
        int a = idx >> 7, k = idx & 127;
        As[k * PAD + a] = out[(size_t)(r0 + a) * D + k];
        Bs[k * PAD + a] = wout[(size_t)a * D + k];
    }
    __syncthreads();
    const int tx = tid & 15, ty = tid >> 4;
    const int rr = ty * 8, cc = tx * 8;
    float acc[8][8] = {};
    for (int k = 0; k < 128; ++k) {
        float a[8], b[8];
        *reinterpret_cast<float4*>(&a[0]) = *reinterpret_cast<const float4*>(&As[k * PAD + rr]);
        *reinterpret_cast<float4*>(&a[4]) = *reinterpret_cast<const float4*>(&As[k * PAD + rr + 4]);
        *reinterpret_cast<float4*>(&b[0]) = *reinterpret_cast<const float4*>(&Bs[k * PAD + cc]);
        *reinterpret_cast<float4*>(&b[4]) = *reinterpret_cast<const float4*>(&Bs[k * PAD + cc + 4]);
        #pragma unroll
        for (int i = 0; i < 8; ++i)
            #pragma unroll
            for (int j = 0; j < 8; ++j)
                acc[i][j] = fmaf(a[i], b[j], acc[i][j]);
    }
    #pragma unroll
    for (int i = 0; i < 8; ++i) {
        float4 o0 = {acc[i][0], acc[i][1], acc[i][2], acc[i][3]};
        float4 o1 = {acc[i][4], acc[i][5], acc[i][6], acc[i][7]};
        *reinterpret_cast<float4*>(&out[(size_t)(r0 + rr + i) * D + cc])     = o0;
        *reinterpret_cast<float4*>(&out[(size_t)(r0 + rr + i) * D + cc + 4]) = o1;
    }
}

extern "C" void kernel_launch(void* const* d_in, const int* in_sizes, int n_in,
                              void* d_out, int out_size, void* d_ws, size_t ws_size,
                              hipStream_t stream) {
    const float* emb  = (const float*)d_in[0];
    const int*   seg  = (const int*)d_in[1];
    const float* watt = (const float*)d_in[3];
    const float* wout = (const float*)d_in[4];
    float* out = (float*)d_out;

    k_fused<<<NBLK, 256, 0, stream>>>(emb, seg, watt, out);
    k_proj <<<S_SEG / 128, 256, 0, stream>>>(out, wout);
}

// Round 11
// 168.361 us; speedup vs baseline: 1.2328x; 1.2328x over previous
//
#include <hip/hip_runtime.h>
#include <hip/hip_bf16.h>

#define N_ELEM 1000000
#define D 128
#define S_SEG 65536
#define SEGW 8            // segments per wave: NBLK*4 waves * SEGW == S_SEG
#define NBLK 2048         // 8192 waves (full-occupancy regime, best so far)
#define NEG_BIG (-1e30f)

// 32-lane xor-reduce (offsets 1..16 never cross the 32-lane half).
__device__ __forceinline__ float halfReduce(float d) {
    #pragma unroll
    for (int off = 1; off <= 16; off <<= 1)
        d += __shfl_xor(d, off, 64);
    return d;
}

__device__ __forceinline__ float dot4(float4 v, float4 w) {
    return fmaf(v.x, w.x, fmaf(v.y, w.y, fmaf(v.z, w.z, v.w * w.w)));
}

// Online-softmax step; valid==false => exact no-op (p=0, m unchanged, scale=1).
__device__ __forceinline__ void osm_step(float& m, float& l, float4& a,
                                         float d, float4 v, bool valid) {
    float mn = valid ? fmaxf(m, d) : m;
    float scale = __expf(m - mn);
    float p = valid ? __expf(d - mn) : 0.f;
    m = mn;
    l = fmaf(l, scale, p);
    a.x = fmaf(a.x, scale, p * v.x);
    a.y = fmaf(a.y, scale, p * v.y);
    a.z = fmaf(a.z, scale, p * v.z);
    a.w = fmaf(a.w, scale, p * v.w);
}

// Merge state 2 into state 1 (associative; safe for empty states).
__device__ __forceinline__ void osm_merge(float& m1, float& l1, float4& a1,
                                          float m2, float l2, float4 a2) {
    float m = fmaxf(m1, m2);
    float s1 = __expf(m1 - m), s2 = __expf(m2 - m);
    l1 = l1 * s1 + l2 * s2;
    a1.x = a1.x * s1 + a2.x * s2;
    a1.y = a1.y * s1 + a2.y * s2;
    a1.z = a1.z * s1 + a2.z * s2;
    a1.w = a1.w * s1 + a2.w * s2;
    m1 = m;
}

// K1: UNCHANGED from round 9 (best measured: 178.7 us total).
// One wave owns SEGW consecutive segments; single streaming pass, dist-2
// software pipeline, inline binary-search bounds, no atomics, no zero-init.
__global__ __launch_bounds__(256, 6) void k_fused(
        const float* __restrict__ emb, const int* __restrict__ seg,
        const float* __restrict__ watt, float* __restrict__ out) {
    const int lane = threadIdx.x & 63;
    const int half = lane >> 5;          // row parity this lane covers
    const int hl   = lane & 31;          // lane within half: dims 4*hl..4*hl+3
    const int wid  = blockIdx.x * 4 + (threadIdx.x >> 6);
    const float4 wv = reinterpret_cast<const float4*>(watt)[hl];
    const float4* emb4 = reinterpret_cast<const float4*>(emb);
    float4* out4 = reinterpret_cast<float4*>(out);

    const int s0 = wid * SEGW;
    int lo = 0;
    if (lane <= SEGW) {
        const int target = s0 + lane;
        int hi = N_ELEM;
        while (lo < hi) {
            int mid = (lo + hi) >> 1;
            if (seg[mid] < target) lo = mid + 1; else hi = mid;
        }
    }

    #pragma unroll 1
    for (int si = 0; si < SEGW; ++si) {
        const int beg = __shfl(lo, si, 64);
        const int end = __shfl(lo, si + 1, 64);
        float  mA = NEG_BIG, lA = 0.f; float4 aA = {0.f, 0.f, 0.f, 0.f};
        float  mB = NEG_BIG, lB = 0.f; float4 aB = {0.f, 0.f, 0.f, 0.f};
        if (beg < end) {
            float4 c0 = emb4[(size_t)min(beg +     half, N_ELEM - 1) * 32 + hl];
            float4 c1 = emb4[(size_t)min(beg + 2 + half, N_ELEM - 1) * 32 + hl];
            float4 c2 = emb4[(size_t)min(beg + 4 + half, N_ELEM - 1) * 32 + hl];
            float4 c3 = emb4[(size_t)min(beg + 6 + half, N_ELEM - 1) * 32 + hl];
            #pragma unroll 1
            for (int e = beg; e < end; e += 4) {
                float4 n0 = emb4[(size_t)min(e + 8  + half, N_ELEM - 1) * 32 + hl];
                float4 n1 = emb4[(size_t)min(e + 10 + half, N_ELEM - 1) * 32 + hl];
                float d0 = halfReduce(dot4(c0, wv));
                float d1 = halfReduce(dot4(c1, wv));
                osm_step(mA, lA, aA, d0, c0, (e +     half) < end);
                osm_step(mB, lB, aB, d1, c1, (e + 2 + half) < end);
                c0 = c2; c1 = c3; c2 = n0; c3 = n1;
            }
        }
        osm_merge(mA, lA, aA, mB, lB, aB);
        float  mo  = __shfl_xor(mA, 32, 64);
        float  lo2 = __shfl_xor(lA, 32, 64);
        float4 ao;
        ao.x = __shfl_xor(aA.x, 32, 64);
        ao.y = __shfl_xor(aA.y, 32, 64);
        ao.z = __shfl_xor(aA.z, 32, 64);
        ao.w = __shfl_xor(aA.w, 32, 64);
        osm_merge(mA, lA, aA, mo, lo2, ao);
        float inv = (lA > 0.f) ? 1.0f / lA : 0.f;        // empty segment -> zeros
        if (half == 0) {
            float4 r = {aA.x * inv, aA.y * inv, aA.z * inv, aA.w * inv};
            out4[(size_t)(s0 + si) * 32 + hl] = r;
        }
    }
}

// K2 (round-11 fix): k-tiled in-place GEMM. Previous version used 132 KB LDS
// -> 1 block/CU -> 1 wave/SIMD, fully exposed LDS latency + serial VALU
// (estimated 40-60 us). Now: two [32][132] tiles = 33.8 KB -> 4 blocks/CU
// (16 waves/CU). Same 8x8 register tile, 4 k-tiles of 32.
#define KT 32
#define PADR 132
__global__ __launch_bounds__(256, 4) void k_proj(
        float* __restrict__ out, const float* __restrict__ wout) {
    __shared__ float As[KT][PADR];   // As[kk][r] = out[r0+r][kt*32+kk]
    __shared__ float Bs[KT][PADR];   // Bs[kk][j] = wout[j][kt*32+kk]
    const int tid = threadIdx.x;
    const int r0 = blockIdx.x * 128;
    const int tx = tid & 15, ty = tid >> 4;
    const int rr = ty * 8, cc = tx * 8;
    float acc[8][8] = {};

    for (int kt = 0; kt < D / KT; ++kt) {
        // stage: 128 rows x 32 ks, each thread 4 float4 chunks per array
        #pragma unroll
        for (int i = 0; i < 4; ++i) {
            int idx = tid + i * 256;           // 0..1023
            int r = idx >> 3, k4 = idx & 7;    // row, float4-chunk in k-tile
            float4 a = *reinterpret_cast<const float4*>(
                &out[(size_t)(r0 + r) * D + kt * KT + k4 * 4]);
            float4 b = *reinterpret_cast<const float4*>(
                &wout[(size_t)r * D + kt * KT + k4 * 4]);
            As[k4 * 4 + 0][r] = a.x; As[k4 * 4 + 1][r] = a.y;
            As[k4 * 4 + 2][r] = a.z; As[k4 * 4 + 3][r] = a.w;
            Bs[k4 * 4 + 0][r] = b.x; Bs[k4 * 4 + 1][r] = b.y;
            Bs[k4 * 4 + 2][r] = b.z; Bs[k4 * 4 + 3][r] = b.w;
        }
        __syncthreads();
        #pragma unroll
        for (int kk = 0; kk < KT; ++kk) {
            float a[8], b[8];
            *reinterpret_cast<float4*>(&a[0]) = *reinterpret_cast<const float4*>(&As[kk][rr]);
            *reinterpret_cast<float4*>(&a[4]) = *reinterpret_cast<const float4*>(&As[kk][rr + 4]);
            *reinterpret_cast<float4*>(&b[0]) = *reinterpret_cast<const float4*>(&Bs[kk][cc]);
            *reinterpret_cast<float4*>(&b[4]) = *reinterpret_cast<const float4*>(&Bs[kk][cc + 4]);
            #pragma unroll
            for (int i = 0; i < 8; ++i)
                #pragma unroll
                for (int j = 0; j < 8; ++j)
                    acc[i][j] = fmaf(a[i], b[j], acc[i][j]);
        }
        __syncthreads();
    }
    #pragma unroll
    for (int i = 0; i < 8; ++i) {
        float4 o0 = {acc[i][0], acc[i][1], acc[i][2], acc[i][3]};
        float4 o1 = {acc[i][4], acc[i][5], acc[i][6], acc[i][7]};
        *reinterpret_cast<float4*>(&out[(size_t)(r0 + rr + i) * D + cc])     = o0;
        *reinterpret_cast<float4*>(&out[(size_t)(r0 + rr + i) * D + cc + 4]) = o1;
    }
}

extern "C" void kernel_launch(void* const* d_in, const int* in_sizes, int n_in,
                              void* d_out, int out_size, void* d_ws, size_t ws_size,
                              hipStream_t stream) {
    const float* emb  = (const float*)d_in[0];
    const int*   seg  = (const int*)d_in[1];
    const float* watt = (const float*)d_in[3];
    const float* wout = (const float*)d_in[4];
    float* out = (float*)d_out;

    k_fused<<<NBLK, 256, 0, stream>>>(emb, seg, watt, out);
    k_proj <<<S_SEG / 128, 256, 0, stream>>>(out, wout);
}

// Round 12
// 166.240 us; speedup vs baseline: 1.2485x; 1.0128x over previous
//
#include <hip/hip_runtime.h>
#include <hip/hip_bf16.h>

#define N_ELEM 1000000
#define D 128
#define S_SEG 65536
#define SEGW 8            // segments per wave: NBLK*4 waves * SEGW == S_SEG
#define NBLK 2048         // 8192 waves (full-occupancy regime, best so far)
#define NEG_BIG (-1e30f)

// DPP-based add of a shifted copy (VALU op — does NOT touch the DS/LDS pipe).
#define DPP_ADD(v, CTRL) \
    v += __int_as_float(__builtin_amdgcn_update_dpp(0, __float_as_int(v), CTRL, 0xF, 0xF, true))

// Per-pair scores: partial = this lane's 4-dim dot contribution.
// Rows: lanes 0-31 hold row e, lanes 32-63 hold row e+1.
// row_shr 1/2/4/8 (+bound_ctrl zeros) leave lane15=sum(0..15), lane31=sum(16..31),
// lane47=sum(32..47), lane63=sum(48..63); row_bcast15 adds each row's lane15 into
// the next row -> lane31=sum(0..31), lane63=sum(32..63). readlane -> SGPRs.
// ZERO DS-pipe traffic (the old __shfl_xor chain was 5 ds_swizzle/row-pair and
// saturated the per-CU LDS pipe at ~3.5 TB/s aggregate).
__device__ __forceinline__ void pairScores(float partial, float& s0, float& s1) {
    float v = partial;
    DPP_ADD(v, 0x111);   // row_shr:1
    DPP_ADD(v, 0x112);   // row_shr:2
    DPP_ADD(v, 0x114);   // row_shr:4
    DPP_ADD(v, 0x118);   // row_shr:8
    DPP_ADD(v, 0x142);   // row_bcast15
    s0 = __int_as_float(__builtin_amdgcn_readlane(__float_as_int(v), 31));
    s1 = __int_as_float(__builtin_amdgcn_readlane(__float_as_int(v), 63));
}

__device__ __forceinline__ float dot4(float4 v, float4 w) {
    return fmaf(v.x, w.x, fmaf(v.y, w.y, fmaf(v.z, w.z, v.w * w.w)));
}

// Online-softmax step; valid==false => exact no-op (p=0, m unchanged, scale=1).
__device__ __forceinline__ void osm_step(float& m, float& l, float4& a,
                                         float d, float4 v, bool valid) {
    float mn = valid ? fmaxf(m, d) : m;
    float scale = __expf(m - mn);
    float p = valid ? __expf(d - mn) : 0.f;
    m = mn;
    l = fmaf(l, scale, p);
    a.x = fmaf(a.x, scale, p * v.x);
    a.y = fmaf(a.y, scale, p * v.y);
    a.z = fmaf(a.z, scale, p * v.z);
    a.w = fmaf(a.w, scale, p * v.w);
}

// Merge state 2 into state 1 (associative; safe for empty states).
__device__ __forceinline__ void osm_merge(float& m1, float& l1, float4& a1,
                                          float m2, float l2, float4 a2) {
    float m = fmaxf(m1, m2);
    float s1 = __expf(m1 - m), s2 = __expf(m2 - m);
    l1 = l1 * s1 + l2 * s2;
    a1.x = a1.x * s1 + a2.x * s2;
    a1.y = a1.y * s1 + a2.y * s2;
    a1.z = a1.z * s1 + a2.z * s2;
    a1.w = a1.w * s1 + a2.w * s2;
    m1 = m;
}

// K1: one wave owns SEGW consecutive segments; single streaming pass, dist-2
// software pipeline, inline binary-search bounds, no atomics, no zero-init.
// ROUND-12: halfReduce (5x ds_swizzle per row-pair, DS-pipe-saturating)
// replaced by pairScores (DPP row_shr/bcast + readlane, pure VALU).
__global__ __launch_bounds__(256, 6) void k_fused(
        const float* __restrict__ emb, const int* __restrict__ seg,
        const float* __restrict__ watt, float* __restrict__ out) {
    const int lane = threadIdx.x & 63;
    const int half = lane >> 5;          // row parity this lane covers
    const int hl   = lane & 31;          // lane within half: dims 4*hl..4*hl+3
    const int wid  = blockIdx.x * 4 + (threadIdx.x >> 6);
    const float4 wv = reinterpret_cast<const float4*>(watt)[hl];
    const float4* emb4 = reinterpret_cast<const float4*>(emb);
    float4* out4 = reinterpret_cast<float4*>(out);

    const int s0 = wid * SEGW;
    int lo = 0;
    if (lane <= SEGW) {
        const int target = s0 + lane;
        int hi = N_ELEM;
        while (lo < hi) {
            int mid = (lo + hi) >> 1;
            if (seg[mid] < target) lo = mid + 1; else hi = mid;
        }
    }

    #pragma unroll 1
    for (int si = 0; si < SEGW; ++si) {
        const int beg = __shfl(lo, si, 64);
        const int end = __shfl(lo, si + 1, 64);
        float  mA = NEG_BIG, lA = 0.f; float4 aA = {0.f, 0.f, 0.f, 0.f};
        float  mB = NEG_BIG, lB = 0.f; float4 aB = {0.f, 0.f, 0.f, 0.f};
        if (beg < end) {
            float4 c0 = emb4[(size_t)min(beg +     half, N_ELEM - 1) * 32 + hl];
            float4 c1 = emb4[(size_t)min(beg + 2 + half, N_ELEM - 1) * 32 + hl];
            float4 c2 = emb4[(size_t)min(beg + 4 + half, N_ELEM - 1) * 32 + hl];
            float4 c3 = emb4[(size_t)min(beg + 6 + half, N_ELEM - 1) * 32 + hl];
            #pragma unroll 1
            for (int e = beg; e < end; e += 4) {
                float4 n0 = emb4[(size_t)min(e + 8  + half, N_ELEM - 1) * 32 + hl];
                float4 n1 = emb4[(size_t)min(e + 10 + half, N_ELEM - 1) * 32 + hl];
                float s0a, s1a, s0b, s1b;
                pairScores(dot4(c0, wv), s0a, s1a);   // rows e, e+1
                pairScores(dot4(c1, wv), s0b, s1b);   // rows e+2, e+3
                float d0 = half ? s1a : s0a;
                float d1 = half ? s1b : s0b;
                osm_step(mA, lA, aA, d0, c0, (e +     half) < end);
                osm_step(mB, lB, aB, d1, c1, (e + 2 + half) < end);
                c0 = c2; c1 = c3; c2 = n0; c3 = n1;
            }
        }
        osm_merge(mA, lA, aA, mB, lB, aB);
        float  mo  = __shfl_xor(mA, 32, 64);
        float  lo2 = __shfl_xor(lA, 32, 64);
        float4 ao;
        ao.x = __shfl_xor(aA.x, 32, 64);
        ao.y = __shfl_xor(aA.y, 32, 64);
        ao.z = __shfl_xor(aA.z, 32, 64);
        ao.w = __shfl_xor(aA.w, 32, 64);
        osm_merge(mA, lA, aA, mo, lo2, ao);
        float inv = (lA > 0.f) ? 1.0f / lA : 0.f;        // empty segment -> zeros
        if (half == 0) {
            float4 r = {aA.x * inv, aA.y * inv, aA.z * inv, aA.w * inv};
            out4[(size_t)(s0 + si) * 32 + hl] = r;
        }
    }
}

// K2: k-tiled in-place GEMM (round-11 version: 33.8 KB LDS -> 4 blocks/CU).
#define KT 32
#define PADR 132
__global__ __launch_bounds__(256, 4) void k_proj(
        float* __restrict__ out, const float* __restrict__ wout) {
    __shared__ float As[KT][PADR];   // As[kk][r] = out[r0+r][kt*32+kk]
    __shared__ float Bs[KT][PADR];   // Bs[kk][j] = wout[j][kt*32+kk]
    const int tid = threadIdx.x;
    const int r0 = blockIdx.x * 128;
    const int tx = tid & 15, ty = tid >> 4;
    const int rr = ty * 8, cc = tx * 8;
    float acc[8][8] = {};

    for (int kt = 0; kt < D / KT; ++kt) {
        #pragma unroll
        for (int i = 0; i < 4; ++i) {
            int idx = tid + i * 256;           // 0..1023
            int r = idx >> 3, k4 = idx & 7;    // row, float4-chunk in k-tile
            float4 a = *reinterpret_cast<const float4*>(
                &out[(size_t)(r0 + r) * D + kt * KT + k4 * 4]);
            float4 b = *reinterpret_cast<const float4*>(
                &wout[(size_t)r * D + kt * KT + k4 * 4]);
            As[k4 * 4 + 0][r] = a.x; As[k4 * 4 + 1][r] = a.y;
            As[k4 * 4 + 2][r] = a.z; As[k4 * 4 + 3][r] = a.w;
            Bs[k4 * 4 + 0][r] = b.x; Bs[k4 * 4 + 1][r] = b.y;
            Bs[k4 * 4 + 2][r] = b.z; Bs[k4 * 4 + 3][r] = b.w;
        }
        __syncthreads();
        #pragma unroll
        for (int kk = 0; kk < KT; ++kk) {
            float a[8], b[8];
            *reinterpret_cast<float4*>(&a[0]) = *reinterpret_cast<const float4*>(&As[kk][rr]);
            *reinterpret_cast<float4*>(&a[4]) = *reinterpret_cast<const float4*>(&As[kk][rr + 4]);
            *reinterpret_cast<float4*>(&b[0]) = *reinterpret_cast<const float4*>(&Bs[kk][cc]);
            *reinterpret_cast<float4*>(&b[4]) = *reinterpret_cast<const float4*>(&Bs[kk][cc + 4]);
            #pragma unroll
            for (int i = 0; i < 8; ++i)
                #pragma unroll
                for (int j = 0; j < 8; ++j)
                    acc[i][j] = fmaf(a[i], b[j], acc[i][j]);
        }
        __syncthreads();
    }
    #pragma unroll
    for (int i = 0; i < 8; ++i) {
        float4 o0 = {acc[i][0], acc[i][1], acc[i][2], acc[i][3]};
        float4 o1 = {acc[i][4], acc[i][5], acc[i][6], acc[i][7]};
        *reinterpret_cast<float4*>(&out[(size_t)(r0 + rr + i) * D + cc])     = o0;
        *reinterpret_cast<float4*>(&out[(size_t)(r0 + rr + i) * D + cc + 4]) = o1;
    }
}

extern "C" void kernel_launch(void* const* d_in, const int* in_sizes, int n_in,
                              void* d_out, int out_size, void* d_ws, size_t ws_size,
                              hipStream_t stream) {
    const float* emb  = (const float*)d_in[0];
    const int*   seg  = (const int*)d_in[1];
    const float* watt = (const float*)d_in[3];
    const float* wout = (const float*)d_in[4];
    float* out = (float*)d_out;

    k_fused<<<NBLK, 256, 0, stream>>>(emb, seg, watt, out);
    k_proj <<<S_SEG / 128, 256, 0, stream>>>(out, wout);
}

// Round 13
// 163.087 us; speedup vs baseline: 1.2727x; 1.0193x over previous
//
#include <hip/hip_runtime.h>
#include <hip/hip_bf16.h>

#define N_ELEM 1000000
#define D 128
#define S_SEG 65536
#define SEGW 8            // segments per wave: NBLK*4 waves * SEGW == S_SEG
#define NBLK 2048
#define NEG_BIG (-1e30f)

// DPP-based add of a shifted copy (pure VALU, no DS pipe).
#define DPP_ADD(v, CTRL) \
    v += __int_as_float(__builtin_amdgcn_update_dpp(0, __float_as_int(v), CTRL, 0xF, 0xF, true))

// Full 64-lane sum via DPP: row_shr 1/2/4/8 + row_bcast15 + row_bcast31,
// then readlane(63) -> SGPR (broadcast free to all lanes).
__device__ __forceinline__ float reduce64(float v) {
    DPP_ADD(v, 0x111);   // row_shr:1
    DPP_ADD(v, 0x112);   // row_shr:2
    DPP_ADD(v, 0x114);   // row_shr:4
    DPP_ADD(v, 0x118);   // row_shr:8
    DPP_ADD(v, 0x142);   // row_bcast:15
    DPP_ADD(v, 0x143);   // row_bcast:31
    return __int_as_float(__builtin_amdgcn_readlane(__float_as_int(v), 63));
}

// Online-softmax step on a float2-per-lane accumulator (row always valid).
__device__ __forceinline__ void osm2(float& m, float& l, float2& a,
                                     float d, float2 v) {
    float mn = fmaxf(m, d);
    float sc = __expf(m - mn);
    float p  = __expf(d - mn);
    m = mn;
    l = fmaf(l, sc, p);
    a.x = fmaf(a.x, sc, p * v.x);
    a.y = fmaf(a.y, sc, p * v.y);
}

// K1 (round-13): CONTINUOUS-STREAM refactor. One row per wave-load
// (float2/lane = 512B); the wave's SEGW segments form ONE sequential row
// range, consumed with a 4-deep register prefetch that NEVER drains --
// segment boundaries are wave-uniform branches that finalize+reset state
// between consumes while prefetched loads stay in flight. This removes the
// per-segment prologue latency-drain (~1-2K cyc x 8/wave) and epilogue
// cross-half shuffles (A/B merge is pure VALU now), and has zero masking
// waste. emb reads HBM exactly once; no atomics; no zero-init.
__global__ __launch_bounds__(256, 6) void k_fused(
        const float* __restrict__ emb, const int* __restrict__ seg,
        const float* __restrict__ watt, float* __restrict__ out) {
    const int lane = threadIdx.x & 63;
    const int wid  = blockIdx.x * 4 + (threadIdx.x >> 6);
    const float2 wv = reinterpret_cast<const float2*>(watt)[lane];
    const float2* emb2 = reinterpret_cast<const float2*>(emb);
    float2* out2 = reinterpret_cast<float2*>(out);

    const int s0 = wid * SEGW;
    // lane i (i<=SEGW) holds lower_bound(seg, s0+i)
    int lo = 0;
    if (lane <= SEGW) {
        int target = s0 + lane, hi = N_ELEM;
        while (lo < hi) {
            int mid = (lo + hi) >> 1;
            if (seg[mid] < target) lo = mid + 1; else hi = mid;
        }
    }

    int si = 0;
    int e      = __shfl(lo, 0, 64);      // row cursor (wave-uniform)
    int endCur = __shfl(lo, 1, 64);      // end of current segment

    float mA = NEG_BIG, lA = 0.f; float2 aA = {0.f, 0.f};
    float mB = NEG_BIG, lB = 0.f; float2 aB = {0.f, 0.f};

    // prologue: prefetch rows e..e+3 (clamped; tail over-reads are consumed
    // never -- si==SEGW guards -- or belong to this wave's own range)
    float2 r0 = emb2[(size_t)min(e + 0, N_ELEM - 1) * 64 + lane];
    float2 r1 = emb2[(size_t)min(e + 1, N_ELEM - 1) * 64 + lane];
    float2 r2 = emb2[(size_t)min(e + 2, N_ELEM - 1) * 64 + lane];
    float2 r3 = emb2[(size_t)min(e + 3, N_ELEM - 1) * 64 + lane];
    int p = e + 4;

#define FIN() do {                                                        \
        float mm = fmaxf(mA, mB);                                         \
        float w1 = __expf(mA - mm), w2 = __expf(mB - mm);                 \
        float ll = lA * w1 + lB * w2;                                     \
        float inv = (ll > 0.f) ? 1.0f / ll : 0.f;                         \
        float2 r;                                                         \
        r.x = (aA.x * w1 + aB.x * w2) * inv;                              \
        r.y = (aA.y * w1 + aB.y * w2) * inv;                              \
        out2[(size_t)(s0 + si) * 64 + lane] = r;                          \
        mA = mB = NEG_BIG; lA = lB = 0.f;                                 \
        aA.x = aA.y = aB.x = aB.y = 0.f;                                  \
        ++si;                                                             \
        if (si < SEGW) endCur = __shfl(lo, si + 1, 64);                   \
    } while (0)

#define SLOT(R, MS, LS, AS) do {                                          \
        while (si < SEGW && e == endCur) FIN();                           \
        if (si < SEGW) {                                                  \
            float d = reduce64(fmaf(R.x, wv.x, R.y * wv.y));              \
            osm2(MS, LS, AS, d, R);                                       \
            ++e;                                                          \
        }                                                                 \
    } while (0)

    #pragma unroll 1
    while (si < SEGW) {
        // issue next 4 sequential row loads (addresses independent of
        // segmentation -> pipeline never drains at boundaries)
        float2 n0 = emb2[(size_t)min(p + 0, N_ELEM - 1) * 64 + lane];
        float2 n1 = emb2[(size_t)min(p + 1, N_ELEM - 1) * 64 + lane];
        float2 n2 = emb2[(size_t)min(p + 2, N_ELEM - 1) * 64 + lane];
        float2 n3 = emb2[(size_t)min(p + 3, N_ELEM - 1) * 64 + lane];
        p += 4;
        SLOT(r0, mA, lA, aA);
        SLOT(r1, mB, lB, aB);
        SLOT(r2, mA, lA, aA);
        SLOT(r3, mB, lB, aB);
        r0 = n0; r1 = n1; r2 = n2; r3 = n3;
    }
#undef SLOT
#undef FIN
}

// K2: k-tiled in-place GEMM (round-11 version: 33.8 KB LDS -> 4 blocks/CU).
#define KT 32
#define PADR 132
__global__ __launch_bounds__(256, 4) void k_proj(
        float* __restrict__ out, const float* __restrict__ wout) {
    __shared__ float As[KT][PADR];   // As[kk][r] = out[r0+r][kt*32+kk]
    __shared__ float Bs[KT][PADR];   // Bs[kk][j] = wout[j][kt*32+kk]
    const int tid = threadIdx.x;
    const int r0 = blockIdx.x * 128;
    const int tx = tid & 15, ty = tid >> 4;
    const int rr = ty * 8, cc = tx * 8;
    float acc[8][8] = {};

    for (int kt = 0; kt < D / KT; ++kt) {
        #pragma unroll
        for (int i = 0; i < 4; ++i) {
            int idx = tid + i * 256;           // 0..1023
            int r = idx >> 3, k4 = idx & 7;    // row, float4-chunk in k-tile
            float4 a = *reinterpret_cast<const float4*>(
                &out[(size_t)(r0 + r) * D + kt * KT + k4 * 4]);
            float4 b = *reinterpret_cast<const float4*>(
                &wout[(size_t)r * D + kt * KT + k4 * 4]);
            As[k4 * 4 + 0][r] = a.x; As[k4 * 4 + 1][r] = a.y;
            As[k4 * 4 + 2][r] = a.z; As[k4 * 4 + 3][r] = a.w;
            Bs[k4 * 4 + 0][r] = b.x; Bs[k4 * 4 + 1][r] = b.y;
            Bs[k4 * 4 + 2][r] = b.z; Bs[k4 * 4 + 3][r] = b.w;
        }
        __syncthreads();
        #pragma unroll
        for (int kk = 0; kk < KT; ++kk) {
            float a[8], b[8];
            *reinterpret_cast<float4*>(&a[0]) = *reinterpret_cast<const float4*>(&As[kk][rr]);
            *reinterpret_cast<float4*>(&a[4]) = *reinterpret_cast<const float4*>(&As[kk][rr + 4]);
            *reinterpret_cast<float4*>(&b[0]) = *reinterpret_cast<const float4*>(&Bs[kk][cc]);
            *reinterpret_cast<float4*>(&b[4]) = *reinterpret_cast<const float4*>(&Bs[kk][cc + 4]);
            #pragma unroll
            for (int i = 0; i < 8; ++i)
                #pragma unroll
                for (int j = 0; j < 8; ++j)
                    acc[i][j] = fmaf(a[i], b[j], acc[i][j]);
        }
        __syncthreads();
    }
    #pragma unroll
    for (int i = 0; i < 8; ++i) {
        float4 o0 = {acc[i][0], acc[i][1], acc[i][2], acc[i][3]};
        float4 o1 = {acc[i][4], acc[i][5], acc[i][6], acc[i][7]};
        *reinterpret_cast<float4*>(&out[(size_t)(r0 + rr + i) * D + cc])     = o0;
        *reinterpret_cast<float4*>(&out[(size_t)(r0 + rr + i) * D + cc + 4]) = o1;
    }
}

extern "C" void kernel_launch(void* const* d_in, const int* in_sizes, int n_in,
                              void* d_out, int out_size, void* d_ws, size_t ws_size,
                              hipStream_t stream) {
    const float* emb  = (const float*)d_in[0];
    const int*   seg  = (const int*)d_in[1];
    const float* watt = (const float*)d_in[3];
    const float* wout = (const float*)d_in[4];
    float* out = (float*)d_out;

    k_fused<<<NBLK, 256, 0, stream>>>(emb, seg, watt, out);
    k_proj <<<S_SEG / 128, 256, 0, stream>>>(out, wout);
}

// Round 14
// 161.422 us; speedup vs baseline: 1.2858x; 1.0103x over previous
//
#include <hip/hip_runtime.h>
#include <hip/hip_bf16.h>

#define N_ELEM 1000000
#define D 128
#define S_SEG 65536
#define SEGW 8            // segments per wave: NBLK*4 waves * SEGW == S_SEG
#define NBLK 2048
#define NEG_BIG (-1e30f)

// DPP-based add of a shifted copy (pure VALU, no DS pipe).
#define DPP_ADD(v, CTRL) \
    v += __int_as_float(__builtin_amdgcn_update_dpp(0, __float_as_int(v), CTRL, 0xF, 0xF, true))

// Full 64-lane sum via DPP: row_shr 1/2/4/8 + row_bcast15 + row_bcast31,
// then readlane(63) -> SGPR (broadcast free to all lanes).
__device__ __forceinline__ float reduce64(float v) {
    DPP_ADD(v, 0x111);   // row_shr:1
    DPP_ADD(v, 0x112);   // row_shr:2
    DPP_ADD(v, 0x114);   // row_shr:4
    DPP_ADD(v, 0x118);   // row_shr:8
    DPP_ADD(v, 0x142);   // row_bcast:15
    DPP_ADD(v, 0x143);   // row_bcast:31
    return __int_as_float(__builtin_amdgcn_readlane(__float_as_int(v), 63));
}

// Online-softmax step on a float2-per-lane accumulator (row always valid).
__device__ __forceinline__ void osm2(float& m, float& l, float2& a,
                                     float d, float2 v) {
    float mn = fmaxf(m, d);
    float sc = __expf(m - mn);
    float p  = __expf(d - mn);
    m = mn;
    l = fmaf(l, sc, p);
    a.x = fmaf(a.x, sc, p * v.x);
    a.y = fmaf(a.y, sc, p * v.y);
}

// K1 (round-14): continuous-stream kernel, prefetch depth 4 -> 8 rows.
// 8 x 512B = 4 KB in flight per wave (~32 MB chip-wide) -- the one Little's
// law lever never cleanly tested (R9's depth test drained every segment;
// this structure never drains). Everything else identical to round 13.
__global__ __launch_bounds__(256, 6) void k_fused(
        const float* __restrict__ emb, const int* __restrict__ seg,
        const float* __restrict__ watt, float* __restrict__ out) {
    const int lane = threadIdx.x & 63;
    const int wid  = blockIdx.x * 4 + (threadIdx.x >> 6);
    const float2 wv = reinterpret_cast<const float2*>(watt)[lane];
    const float2* emb2 = reinterpret_cast<const float2*>(emb);
    float2* out2 = reinterpret_cast<float2*>(out);

    const int s0 = wid * SEGW;
    // lane i (i<=SEGW) holds lower_bound(seg, s0+i)
    int lo = 0;
    if (lane <= SEGW) {
        int target = s0 + lane, hi = N_ELEM;
        while (lo < hi) {
            int mid = (lo + hi) >> 1;
            if (seg[mid] < target) lo = mid + 1; else hi = mid;
        }
    }

    int si = 0;
    int e      = __shfl(lo, 0, 64);      // row cursor (wave-uniform)
    int endCur = __shfl(lo, 1, 64);      // end of current segment

    float mA = NEG_BIG, lA = 0.f; float2 aA = {0.f, 0.f};
    float mB = NEG_BIG, lB = 0.f; float2 aB = {0.f, 0.f};

    // prologue: prefetch rows e..e+7 (clamped)
    float2 r0 = emb2[(size_t)min(e + 0, N_ELEM - 1) * 64 + lane];
    float2 r1 = emb2[(size_t)min(e + 1, N_ELEM - 1) * 64 + lane];
    float2 r2 = emb2[(size_t)min(e + 2, N_ELEM - 1) * 64 + lane];
    float2 r3 = emb2[(size_t)min(e + 3, N_ELEM - 1) * 64 + lane];
    float2 r4 = emb2[(size_t)min(e + 4, N_ELEM - 1) * 64 + lane];
    float2 r5 = emb2[(size_t)min(e + 5, N_ELEM - 1) * 64 + lane];
    float2 r6 = emb2[(size_t)min(e + 6, N_ELEM - 1) * 64 + lane];
    float2 r7 = emb2[(size_t)min(e + 7, N_ELEM - 1) * 64 + lane];
    int p = e + 8;

#define FIN() do {                                                        \
        float mm = fmaxf(mA, mB);                                         \
        float w1 = __expf(mA - mm), w2 = __expf(mB - mm);                 \
        float ll = lA * w1 + lB * w2;                                     \
        float inv = (ll > 0.f) ? 1.0f / ll : 0.f;                         \
        float2 r;                                                         \
        r.x = (aA.x * w1 + aB.x * w2) * inv;                              \
        r.y = (aA.y * w1 + aB.y * w2) * inv;                              \
        out2[(size_t)(s0 + si) * 64 + lane] = r;                          \
        mA = mB = NEG_BIG; lA = lB = 0.f;                                 \
        aA.x = aA.y = aB.x = aB.y = 0.f;                                  \
        ++si;                                                             \
        if (si < SEGW) endCur = __shfl(lo, si + 1, 64);                   \
    } while (0)

#define SLOT(R, MS, LS, AS) do {                                          \
        while (si < SEGW && e == endCur) FIN();                           \
        if (si < SEGW) {                                                  \
            float d = reduce64(fmaf(R.x, wv.x, R.y * wv.y));              \
            osm2(MS, LS, AS, d, R);                                       \
            ++e;                                                          \
        }                                                                 \
    } while (0)

    #pragma unroll 1
    while (si < SEGW) {
        // issue next 8 sequential row loads (addresses independent of
        // segmentation -> pipeline never drains at boundaries)
        float2 n0 = emb2[(size_t)min(p + 0, N_ELEM - 1) * 64 + lane];
        float2 n1 = emb2[(size_t)min(p + 1, N_ELEM - 1) * 64 + lane];
        float2 n2 = emb2[(size_t)min(p + 2, N_ELEM - 1) * 64 + lane];
        float2 n3 = emb2[(size_t)min(p + 3, N_ELEM - 1) * 64 + lane];
        float2 n4 = emb2[(size_t)min(p + 4, N_ELEM - 1) * 64 + lane];
        float2 n5 = emb2[(size_t)min(p + 5, N_ELEM - 1) * 64 + lane];
        float2 n6 = emb2[(size_t)min(p + 6, N_ELEM - 1) * 64 + lane];
        float2 n7 = emb2[(size_t)min(p + 7, N_ELEM - 1) * 64 + lane];
        p += 8;
        SLOT(r0, mA, lA, aA);
        SLOT(r1, mB, lB, aB);
        SLOT(r2, mA, lA, aA);
        SLOT(r3, mB, lB, aB);
        SLOT(r4, mA, lA, aA);
        SLOT(r5, mB, lB, aB);
        SLOT(r6, mA, lA, aA);
        SLOT(r7, mB, lB, aB);
        r0 = n0; r1 = n1; r2 = n2; r3 = n3;
        r4 = n4; r5 = n5; r6 = n6; r7 = n7;
    }
#undef SLOT
#undef FIN
}

// K2: k-tiled in-place GEMM (round-11 version: 33.8 KB LDS -> 4 blocks/CU).
#define KT 32
#define PADR 132
__global__ __launch_bounds__(256, 4) void k_proj(
        float* __restrict__ out, const float* __restrict__ wout) {
    __shared__ float As[KT][PADR];   // As[kk][r] = out[r0+r][kt*32+kk]
    __shared__ float Bs[KT][PADR];   // Bs[kk][j] = wout[j][kt*32+kk]
    const int tid = threadIdx.x;
    const int r0 = blockIdx.x * 128;
    const int tx = tid & 15, ty = tid >> 4;
    const int rr = ty * 8, cc = tx * 8;
    float acc[8][8] = {};

    for (int kt = 0; kt < D / KT; ++kt) {
        #pragma unroll
        for (int i = 0; i < 4; ++i) {
            int idx = tid + i * 256;           // 0..1023
            int r = idx >> 3, k4 = idx & 7;    // row, float4-chunk in k-tile
            float4 a = *reinterpret_cast<const float4*>(
                &out[(size_t)(r0 + r) * D + kt * KT + k4 * 4]);
            float4 b = *reinterpret_cast<const float4*>(
                &wout[(size_t)r * D + kt * KT + k4 * 4]);
            As[k4 * 4 + 0][r] = a.x; As[k4 * 4 + 1][r] = a.y;
            As[k4 * 4 + 2][r] = a.z; As[k4 * 4 + 3][r] = a.w;
            Bs[k4 * 4 + 0][r] = b.x; Bs[k4 * 4 + 1][r] = b.y;
            Bs[k4 * 4 + 2][r] = b.z; Bs[k4 * 4 + 3][r] = b.w;
        }
        __syncthreads();
        #pragma unroll
        for (int kk = 0; kk < KT; ++kk) {
            float a[8], b[8];
            *reinterpret_cast<float4*>(&a[0]) = *reinterpret_cast<const float4*>(&As[kk][rr]);
            *reinterpret_cast<float4*>(&a[4]) = *reinterpret_cast<const float4*>(&As[kk][rr + 4]);
            *reinterpret_cast<float4*>(&b[0]) = *reinterpret_cast<const float4*>(&Bs[kk][cc]);
            *reinterpret_cast<float4*>(&b[4]) = *reinterpret_cast<const float4*>(&Bs[kk][cc + 4]);
            #pragma unroll
            for (int i = 0; i < 8; ++i)
                #pragma unroll
                for (int j = 0; j < 8; ++j)
                    acc[i][j] = fmaf(a[i], b[j], acc[i][j]);
        }
        __syncthreads();
    }
    #pragma unroll
    for (int i = 0; i < 8; ++i) {
        float4 o0 = {acc[i][0], acc[i][1], acc[i][2], acc[i][3]};
        float4 o1 = {acc[i][4], acc[i][5], acc[i][6], acc[i][7]};
        *reinterpret_cast<float4*>(&out[(size_t)(r0 + rr + i) * D + cc])     = o0;
        *reinterpret_cast<float4*>(&out[(size_t)(r0 + rr + i) * D + cc + 4]) = o1;
    }
}

extern "C" void kernel_launch(void* const* d_in, const int* in_sizes, int n_in,
                              void* d_out, int out_size, void* d_ws, size_t ws_size,
                              hipStream_t stream) {
    const float* emb  = (const float*)d_in[0];
    const int*   seg  = (const int*)d_in[1];
    const float* watt = (const float*)d_in[3];
    const float* wout = (const float*)d_in[4];
    float* out = (float*)d_out;

    k_fused<<<NBLK, 256, 0, stream>>>(emb, seg, watt, out);
    k_proj <<<S_SEG / 128, 256, 0, stream>>>(out, wout);
}